// Round 1
// baseline (1194.893 us; speedup 1.0000x reference)
//
#include <hip/hip_runtime.h>

#define N_NODES_C 20000
#define IN_FEAT 256
#define OUT_FEAT 128

// ---------------------------------------------------------------------------
// Kernel 1: h = x @ W   (f32, vector ALU — no fp32 MFMA on CDNA4)
// Tile: 64 rows x 128 cols, K-chunk = 32.
// Thread layout: 256 threads = 32 (tx: 4-col groups) x 8 (ty: 8-row groups).
// x tile stored transposed in LDS ([k][row]) so the 8-row fragment is two
// contiguous float4 reads; W tile [k][col] gives one float4 per thread.
// ---------------------------------------------------------------------------
__global__ __launch_bounds__(256) void gemm_kernel(const float* __restrict__ x,
                                                   const float* __restrict__ w,
                                                   float* __restrict__ h,
                                                   int n_nodes) {
    __shared__ float xs[32][64];    // [k][row]  8 KB
    __shared__ float ws[32][128];   // [k][col] 16 KB
    const int block_row = blockIdx.x * 64;
    const int tid = threadIdx.x;
    const int tx = tid & 31;   // cols tx*4 .. tx*4+3
    const int ty = tid >> 5;   // rows ty*8 .. ty*8+7

    float acc[8][4] = {};

    for (int k0 = 0; k0 < IN_FEAT; k0 += 32) {
        // stage x[block_row..+64][k0..+32] transposed: 2048 elems, 8/thread
        #pragma unroll
        for (int i = tid; i < 64 * 32; i += 256) {
            int r  = i >> 5;   // 0..63
            int kk = i & 31;   // 0..31
            int row = block_row + r;
            xs[kk][r] = (row < n_nodes) ? x[row * IN_FEAT + k0 + kk] : 0.f;
        }
        // stage W[k0..+32][0..128]: 4096 elems as 1024 float4, 4/thread
        #pragma unroll
        for (int i = tid; i < 32 * 128 / 4; i += 256) {
            int kk = i >> 5;   // 0..31
            int c4 = i & 31;   // 0..31 float4 slots
            *reinterpret_cast<float4*>(&ws[kk][c4 * 4]) =
                *reinterpret_cast<const float4*>(&w[(k0 + kk) * OUT_FEAT + c4 * 4]);
        }
        __syncthreads();

        #pragma unroll
        for (int kk = 0; kk < 32; ++kk) {
            float4 b  = *reinterpret_cast<const float4*>(&ws[kk][tx * 4]);
            float4 a0 = *reinterpret_cast<const float4*>(&xs[kk][ty * 8]);
            float4 a1 = *reinterpret_cast<const float4*>(&xs[kk][ty * 8 + 4]);
            float a[8] = {a0.x, a0.y, a0.z, a0.w, a1.x, a1.y, a1.z, a1.w};
            #pragma unroll
            for (int r = 0; r < 8; ++r) {
                acc[r][0] += a[r] * b.x;
                acc[r][1] += a[r] * b.y;
                acc[r][2] += a[r] * b.z;
                acc[r][3] += a[r] * b.w;
            }
        }
        __syncthreads();
    }

    #pragma unroll
    for (int r = 0; r < 8; ++r) {
        int row = block_row + ty * 8 + r;
        if (row < n_nodes) {
            float4 v = make_float4(acc[r][0], acc[r][1], acc[r][2], acc[r][3]);
            *reinterpret_cast<float4*>(&h[row * OUT_FEAT + tx * 4]) = v;
        }
    }
}

// ---------------------------------------------------------------------------
// Kernel 2: out[n][c] = bias[c]   (d_out is poisoned 0xAA before every call)
// ---------------------------------------------------------------------------
__global__ void init_out_kernel(float* __restrict__ out,
                                const float* __restrict__ bias, int n4) {
    int i = blockIdx.x * blockDim.x + threadIdx.x;
    if (i < n4) {
        int f = (i & 31) * 4;  // OUT_FEAT/4 = 32 float4 per row
        float4 b = *reinterpret_cast<const float4*>(&bias[f]);
        reinterpret_cast<float4*>(out)[i] = b;
    }
}

// ---------------------------------------------------------------------------
// Kernel 3: out[row[e]] += h[col[e]]  — 32 lanes/edge, float4 gather,
// 4 hardware f32 atomics (unsafeAtomicAdd -> global_atomic_add_f32).
// ---------------------------------------------------------------------------
__global__ __launch_bounds__(256) void scatter_kernel(const float* __restrict__ h,
                                                      const int* __restrict__ edges,
                                                      float* __restrict__ out,
                                                      int n_edges, int n_nodes) {
    long long gid = (long long)blockIdx.x * blockDim.x + threadIdx.x;
    int e = (int)(gid >> 5);
    int f = ((int)gid & 31) * 4;
    if (e >= n_edges) return;
    int row = edges[e];            // destination
    int col = edges[n_edges + e];  // source
    if ((unsigned)row >= (unsigned)n_nodes || (unsigned)col >= (unsigned)n_nodes) return;
    float4 v = *reinterpret_cast<const float4*>(&h[(long long)col * OUT_FEAT + f]);
    float* dst = &out[(long long)row * OUT_FEAT + f];
    unsafeAtomicAdd(dst + 0, v.x);
    unsafeAtomicAdd(dst + 1, v.y);
    unsafeAtomicAdd(dst + 2, v.z);
    unsafeAtomicAdd(dst + 3, v.w);
}

// ---------------------------------------------------------------------------
// Kernel 4: out = relu(out)
// ---------------------------------------------------------------------------
__global__ void relu_kernel(float* __restrict__ out, int n4) {
    int i = blockIdx.x * blockDim.x + threadIdx.x;
    if (i < n4) {
        float4 v = reinterpret_cast<float4*>(out)[i];
        v.x = fmaxf(v.x, 0.f);
        v.y = fmaxf(v.y, 0.f);
        v.z = fmaxf(v.z, 0.f);
        v.w = fmaxf(v.w, 0.f);
        reinterpret_cast<float4*>(out)[i] = v;
    }
}

extern "C" void kernel_launch(void* const* d_in, const int* in_sizes, int n_in,
                              void* d_out, int out_size, void* d_ws, size_t ws_size,
                              hipStream_t stream) {
    const float* x      = (const float*)d_in[0];
    const int*   edges  = (const int*)d_in[1];
    const float* weight = (const float*)d_in[2];
    const float* bias   = (const float*)d_in[3];
    float* out = (float*)d_out;
    float* h   = (float*)d_ws;   // n_nodes * OUT_FEAT f32 = 10.24 MB

    const int n_nodes = in_sizes[0] / IN_FEAT;   // 20000
    const int n_edges = in_sizes[1] / 2;         // 640000

    // 1) h = x @ W
    int gemm_blocks = (n_nodes + 63) / 64;
    gemm_kernel<<<gemm_blocks, 256, 0, stream>>>(x, weight, h, n_nodes);

    // 2) out = bias
    int n4 = n_nodes * OUT_FEAT / 4;
    init_out_kernel<<<(n4 + 255) / 256, 256, 0, stream>>>(out, bias, n4);

    // 3) scatter-add
    long long work = (long long)n_edges * 32;
    int sc_blocks = (int)((work + 255) / 256);
    scatter_kernel<<<sc_blocks, 256, 0, stream>>>(h, edges, out, n_edges, n_nodes);

    // 4) relu
    relu_kernel<<<(n4 + 255) / 256, 256, 0, stream>>>(out, n4);
}

// Round 2
// 246.581 us; speedup vs baseline: 4.8458x; 4.8458x over previous
//
#include <hip/hip_runtime.h>

#define IN_FEAT 256
#define OUT_FEAT 128

// ---------------------------------------------------------------------------
// Kernel 1: h = x @ W   (f32, vector ALU — no fp32 MFMA on CDNA4)
// ---------------------------------------------------------------------------
__global__ __launch_bounds__(256) void gemm_kernel(const float* __restrict__ x,
                                                   const float* __restrict__ w,
                                                   float* __restrict__ h,
                                                   int n_nodes) {
    __shared__ float xs[32][64];    // [k][row]  8 KB
    __shared__ float ws[32][128];   // [k][col] 16 KB
    const int block_row = blockIdx.x * 64;
    const int tid = threadIdx.x;
    const int tx = tid & 31;   // cols tx*4 .. tx*4+3
    const int ty = tid >> 5;   // rows ty*8 .. ty*8+7

    float acc[8][4] = {};

    for (int k0 = 0; k0 < IN_FEAT; k0 += 32) {
        #pragma unroll
        for (int i = tid; i < 64 * 32; i += 256) {
            int r  = i >> 5;
            int kk = i & 31;
            int row = block_row + r;
            xs[kk][r] = (row < n_nodes) ? x[row * IN_FEAT + k0 + kk] : 0.f;
        }
        #pragma unroll
        for (int i = tid; i < 32 * 128 / 4; i += 256) {
            int kk = i >> 5;
            int c4 = i & 31;
            *reinterpret_cast<float4*>(&ws[kk][c4 * 4]) =
                *reinterpret_cast<const float4*>(&w[(k0 + kk) * OUT_FEAT + c4 * 4]);
        }
        __syncthreads();

        #pragma unroll
        for (int kk = 0; kk < 32; ++kk) {
            float4 b  = *reinterpret_cast<const float4*>(&ws[kk][tx * 4]);
            float4 a0 = *reinterpret_cast<const float4*>(&xs[kk][ty * 8]);
            float4 a1 = *reinterpret_cast<const float4*>(&xs[kk][ty * 8 + 4]);
            float a[8] = {a0.x, a0.y, a0.z, a0.w, a1.x, a1.y, a1.z, a1.w};
            #pragma unroll
            for (int r = 0; r < 8; ++r) {
                acc[r][0] += a[r] * b.x;
                acc[r][1] += a[r] * b.y;
                acc[r][2] += a[r] * b.z;
                acc[r][3] += a[r] * b.w;
            }
        }
        __syncthreads();
    }

    #pragma unroll
    for (int r = 0; r < 8; ++r) {
        int row = block_row + ty * 8 + r;
        if (row < n_nodes) {
            float4 v = make_float4(acc[r][0], acc[r][1], acc[r][2], acc[r][3]);
            *reinterpret_cast<float4*>(&h[row * OUT_FEAT + tx * 4]) = v;
        }
    }
}

// ---------------------------------------------------------------------------
// CSR build stage A: zero the degree/cursor array (ws is poisoned each call)
// ---------------------------------------------------------------------------
__global__ void zero_kernel(int* __restrict__ p, int n) {
    int i = blockIdx.x * blockDim.x + threadIdx.x;
    if (i < n) p[i] = 0;
}

// ---------------------------------------------------------------------------
// CSR build stage B: degree histogram over destination nodes
// ---------------------------------------------------------------------------
__global__ __launch_bounds__(256) void count_kernel(const int* __restrict__ edges,
                                                    int* __restrict__ deg,
                                                    int n_edges, int n_nodes) {
    int e = blockIdx.x * blockDim.x + threadIdx.x;
    if (e >= n_edges) return;
    int row = edges[e];
    if ((unsigned)row < (unsigned)n_nodes) atomicAdd(&deg[row], 1);
}

// ---------------------------------------------------------------------------
// CSR build stage C: exclusive prefix scan of 20k degrees, single block.
// Writes offsets[0..n] and initializes cursor[i] = offsets[i].
// ---------------------------------------------------------------------------
#define SCAN_THREADS 1024
#define SCAN_PER 20   // 1024*20 = 20480 >= 20000
__global__ __launch_bounds__(SCAN_THREADS) void scan_kernel(const int* __restrict__ deg,
                                                            int* __restrict__ offsets,
                                                            int* __restrict__ cursor,
                                                            int n) {
    __shared__ int partial[SCAN_THREADS];
    const int tid = threadIdx.x;
    const int base = tid * SCAN_PER;

    int local[SCAN_PER];
    int sum = 0;
    #pragma unroll
    for (int i = 0; i < SCAN_PER; ++i) {
        int idx = base + i;
        int v = (idx < n) ? deg[idx] : 0;
        local[i] = sum;          // local exclusive prefix
        sum += v;
    }
    partial[tid] = sum;
    __syncthreads();

    // inclusive Hillis-Steele scan over 1024 partials
    for (int off = 1; off < SCAN_THREADS; off <<= 1) {
        int t = (tid >= off) ? partial[tid - off] : 0;
        __syncthreads();
        partial[tid] += t;
        __syncthreads();
    }

    int excl = partial[tid] - sum;   // exclusive base for this thread's chunk
    #pragma unroll
    for (int i = 0; i < SCAN_PER; ++i) {
        int idx = base + i;
        if (idx < n) {
            int o = excl + local[i];
            offsets[idx] = o;
            cursor[idx] = o;
        }
    }
    if (tid == SCAN_THREADS - 1) offsets[n] = partial[SCAN_THREADS - 1];
}

// ---------------------------------------------------------------------------
// CSR build stage D: bucket-fill source indices grouped by destination
// ---------------------------------------------------------------------------
__global__ __launch_bounds__(256) void fill_kernel(const int* __restrict__ edges,
                                                   int* __restrict__ cursor,
                                                   int* __restrict__ col_sorted,
                                                   int n_edges, int n_nodes) {
    int e = blockIdx.x * blockDim.x + threadIdx.x;
    if (e >= n_edges) return;
    int row = edges[e];
    int col = edges[n_edges + e];
    if ((unsigned)row >= (unsigned)n_nodes || (unsigned)col >= (unsigned)n_nodes) return;
    int pos = atomicAdd(&cursor[row], 1);
    col_sorted[pos] = col;
}

// ---------------------------------------------------------------------------
// Kernel 5: atomic-free gather-accumulate, fused bias + ReLU.
// 32 lanes per destination node, one float4 of features per lane.
// ---------------------------------------------------------------------------
__global__ __launch_bounds__(256) void aggregate_kernel(const float* __restrict__ h,
                                                        const int* __restrict__ col_sorted,
                                                        const int* __restrict__ offsets,
                                                        const float* __restrict__ bias,
                                                        float* __restrict__ out,
                                                        int n_nodes) {
    int gid = blockIdx.x * blockDim.x + threadIdx.x;
    int node = gid >> 5;
    int f = (gid & 31) * 4;
    if (node >= n_nodes) return;

    int start = offsets[node];
    int end   = offsets[node + 1];

    float4 acc = make_float4(0.f, 0.f, 0.f, 0.f);
    int e = start;
    // unroll by 2 for memory-level parallelism on the col -> h[col] chain
    for (; e + 1 < end; e += 2) {
        int c0 = col_sorted[e];
        int c1 = col_sorted[e + 1];
        float4 v0 = *reinterpret_cast<const float4*>(&h[(long long)c0 * OUT_FEAT + f]);
        float4 v1 = *reinterpret_cast<const float4*>(&h[(long long)c1 * OUT_FEAT + f]);
        acc.x += v0.x; acc.y += v0.y; acc.z += v0.z; acc.w += v0.w;
        acc.x += v1.x; acc.y += v1.y; acc.z += v1.z; acc.w += v1.w;
    }
    if (e < end) {
        int c0 = col_sorted[e];
        float4 v0 = *reinterpret_cast<const float4*>(&h[(long long)c0 * OUT_FEAT + f]);
        acc.x += v0.x; acc.y += v0.y; acc.z += v0.z; acc.w += v0.w;
    }

    float4 b = *reinterpret_cast<const float4*>(&bias[f]);
    float4 r;
    r.x = fmaxf(acc.x + b.x, 0.f);
    r.y = fmaxf(acc.y + b.y, 0.f);
    r.z = fmaxf(acc.z + b.z, 0.f);
    r.w = fmaxf(acc.w + b.w, 0.f);
    *reinterpret_cast<float4*>(&out[(long long)node * OUT_FEAT + f]) = r;
}

extern "C" void kernel_launch(void* const* d_in, const int* in_sizes, int n_in,
                              void* d_out, int out_size, void* d_ws, size_t ws_size,
                              hipStream_t stream) {
    const float* x      = (const float*)d_in[0];
    const int*   edges  = (const int*)d_in[1];
    const float* weight = (const float*)d_in[2];
    const float* bias   = (const float*)d_in[3];
    float* out = (float*)d_out;

    const int n_nodes = in_sizes[0] / IN_FEAT;   // 20000
    const int n_edges = in_sizes[1] / 2;         // 640000

    // workspace layout (all 16B aligned)
    char* ws = (char*)d_ws;
    size_t off = 0;
    float* h = (float*)(ws + off);              off += (size_t)n_nodes * OUT_FEAT * 4;   // 10.24 MB
    int* cursor = (int*)(ws + off);             off += ((size_t)n_nodes * 4 + 15) & ~15; // 80 KB
    int* offsets = (int*)(ws + off);            off += (((size_t)n_nodes + 1) * 4 + 15) & ~15;
    int* col_sorted = (int*)(ws + off);         off += (size_t)n_edges * 4;              // 2.56 MB

    // 1) h = x @ W
    gemm_kernel<<<(n_nodes + 63) / 64, 256, 0, stream>>>(x, weight, h, n_nodes);

    // 2) CSR build: zero degrees -> histogram -> scan -> fill
    zero_kernel<<<(n_nodes + 255) / 256, 256, 0, stream>>>(cursor, n_nodes);
    count_kernel<<<(n_edges + 255) / 256, 256, 0, stream>>>(edges, cursor, n_edges, n_nodes);
    scan_kernel<<<1, SCAN_THREADS, 0, stream>>>(cursor, offsets, cursor, n_nodes);
    fill_kernel<<<(n_edges + 255) / 256, 256, 0, stream>>>(edges, cursor, col_sorted, n_edges, n_nodes);

    // 3) atomic-free aggregate + bias + relu
    long long work = (long long)n_nodes * 32;
    aggregate_kernel<<<(int)((work + 255) / 256), 256, 0, stream>>>(
        h, col_sorted, offsets, bias, out, n_nodes);
}

// Round 3
// 202.840 us; speedup vs baseline: 5.8908x; 1.2156x over previous
//
#include <hip/hip_runtime.h>

#define IN_FEAT 256
#define OUT_FEAT 128

typedef __bf16 bf16x8 __attribute__((ext_vector_type(8)));
typedef float f32x4 __attribute__((ext_vector_type(4)));

// bf16 (stored as ushort) -> f32 unpack helpers
__device__ __forceinline__ float bf_lo(unsigned u) {
    return __builtin_bit_cast(float, u << 16);
}
__device__ __forceinline__ float bf_hi(unsigned u) {
    return __builtin_bit_cast(float, u & 0xffff0000u);
}

// ---------------------------------------------------------------------------
// prep_count: (a) w_t[n][k] = bf16(w[k][n])  (64 KB, consumed by gemm)
//             (b) degree histogram of destination nodes (cursor pre-zeroed
//                 by hipMemsetAsync). int4-vectorized edge reads.
// ---------------------------------------------------------------------------
#define WT_THREADS (OUT_FEAT * IN_FEAT / 8)   // 4096
__global__ __launch_bounds__(256) void prep_count_kernel(
        const float* __restrict__ w, unsigned short* __restrict__ wt,
        const int* __restrict__ edges, int* __restrict__ deg,
        int n_edges, int n_nodes) {
    int t = blockIdx.x * blockDim.x + threadIdx.x;
    if (t < WT_THREADS) {
        int n  = t >> 5;          // 0..127 output col
        int k0 = (t & 31) * 8;    // k chunk
        union { unsigned short s[8]; uint4 u; } p;
        #pragma unroll
        for (int i = 0; i < 8; ++i) {
            __bf16 b = (__bf16)w[(k0 + i) * OUT_FEAT + n];
            p.s[i] = __builtin_bit_cast(unsigned short, b);
        }
        *reinterpret_cast<uint4*>(&wt[n * IN_FEAT + k0]) = p.u;
    } else {
        int e4 = (t - WT_THREADS) * 4;
        if (e4 >= n_edges) return;
        int4 r = *reinterpret_cast<const int4*>(&edges[e4]);
        if ((unsigned)r.x < (unsigned)n_nodes) atomicAdd(&deg[r.x], 1);
        if ((unsigned)r.y < (unsigned)n_nodes) atomicAdd(&deg[r.y], 1);
        if ((unsigned)r.z < (unsigned)n_nodes) atomicAdd(&deg[r.z], 1);
        if ((unsigned)r.w < (unsigned)n_nodes) atomicAdd(&deg[r.w], 1);
    }
}

// ---------------------------------------------------------------------------
// gemm: h(bf16)[row][n] = x(f32)[row][k] @ W[k][n], MFMA 16x16x32 bf16.
// LDS-free: W^T frags from L2-resident wt, x converted in-register.
// Swapped operands mfma(b, a, acc): D frag -> lane holds row = lane&15,
// cols n = nf*16 + (lane>>4)*4 + reg  (4 consecutive cols -> 8 B store).
// Wave = 16 rows x 128 cols; block = 4 waves = 64 rows.
// ---------------------------------------------------------------------------
__global__ __launch_bounds__(256) void gemm_kernel(
        const float* __restrict__ x, const unsigned short* __restrict__ wt,
        unsigned short* __restrict__ h, int n_nodes) {
    const int tid = threadIdx.x;
    const int wid = tid >> 6;
    const int l   = tid & 63;
    const int lr  = l & 15;    // row-in-wave / operand idx
    const int lg  = l >> 4;    // k-subgroup
    const int row = blockIdx.x * 64 + wid * 16 + lr;
    const int rowc = row < n_nodes ? row : n_nodes - 1;
    const float* xrow = x + (long long)rowc * IN_FEAT;

    f32x4 acc[8];
    #pragma unroll
    for (int i = 0; i < 8; ++i) acc[i] = (f32x4){0.f, 0.f, 0.f, 0.f};

    #pragma unroll 2
    for (int kk = 0; kk < 8; ++kk) {
        const int k0 = kk * 32 + lg * 8;
        float4 xa = *reinterpret_cast<const float4*>(xrow + k0);
        float4 xb = *reinterpret_cast<const float4*>(xrow + k0 + 4);
        bf16x8 a;
        a[0] = (__bf16)xa.x; a[1] = (__bf16)xa.y;
        a[2] = (__bf16)xa.z; a[3] = (__bf16)xa.w;
        a[4] = (__bf16)xb.x; a[5] = (__bf16)xb.y;
        a[6] = (__bf16)xb.z; a[7] = (__bf16)xb.w;
        #pragma unroll
        for (int nf = 0; nf < 8; ++nf) {
            uint4 braw = *reinterpret_cast<const uint4*>(
                &wt[(nf * 16 + lr) * IN_FEAT + k0]);
            bf16x8 b = __builtin_bit_cast(bf16x8, braw);
            acc[nf] = __builtin_amdgcn_mfma_f32_16x16x32_bf16(b, a, acc[nf], 0, 0, 0);
        }
    }

    if (row < n_nodes) {
        unsigned short* hrow = h + (long long)row * OUT_FEAT;
        #pragma unroll
        for (int nf = 0; nf < 8; ++nf) {
            union { unsigned short s[4]; uint2 u; } p;
            #pragma unroll
            for (int r = 0; r < 4; ++r) {
                __bf16 b = (__bf16)acc[nf][r];
                p.s[r] = __builtin_bit_cast(unsigned short, b);
            }
            *reinterpret_cast<uint2*>(&hrow[nf * 16 + lg * 4]) = p.u;
        }
    }
}

// ---------------------------------------------------------------------------
// scan: exclusive prefix over 20k degrees, single block, shfl-based.
// Writes offsets[0..n] and cursor[i] = offsets[i].
// ---------------------------------------------------------------------------
#define SCAN_THREADS 1024
#define SCAN_PER 20
__global__ __launch_bounds__(SCAN_THREADS) void scan_kernel(
        const int* __restrict__ deg, int* __restrict__ offsets,
        int* __restrict__ cursor, int n) {
    __shared__ int wsum[16];
    __shared__ int woff[16];
    const int tid = threadIdx.x;
    const int lane = tid & 63;
    const int w = tid >> 6;
    const int base = tid * SCAN_PER;

    int local[SCAN_PER];
    int sum = 0;
    #pragma unroll
    for (int i = 0; i < SCAN_PER; ++i) {
        int idx = base + i;
        int v = (idx < n) ? deg[idx] : 0;
        local[i] = sum;
        sum += v;
    }
    // inclusive scan of per-thread sums within wave
    int incl = sum;
    #pragma unroll
    for (int d = 1; d < 64; d <<= 1) {
        int t = __shfl_up(incl, d, 64);
        if (lane >= d) incl += t;
    }
    if (lane == 63) wsum[w] = incl;
    __syncthreads();
    if (w == 0) {
        int v = (lane < 16) ? wsum[lane] : 0;
        int iv = v;
        #pragma unroll
        for (int d = 1; d < 16; d <<= 1) {
            int t = __shfl_up(iv, d, 64);
            if (lane >= d) iv += t;
        }
        if (lane < 16) woff[lane] = iv - v;   // exclusive wave base
    }
    __syncthreads();

    int excl = woff[w] + (incl - sum);
    #pragma unroll
    for (int i = 0; i < SCAN_PER; ++i) {
        int idx = base + i;
        if (idx < n) {
            int o = excl + local[i];
            offsets[idx] = o;
            cursor[idx] = o;
        }
    }
    if (tid == SCAN_THREADS - 1) offsets[n] = excl + sum;
}

// ---------------------------------------------------------------------------
// fill: bucket source indices by destination. int4-vectorized.
// ---------------------------------------------------------------------------
__global__ __launch_bounds__(256) void fill_kernel(
        const int* __restrict__ edges, int* __restrict__ cursor,
        int* __restrict__ col_sorted, int n_edges, int n_nodes) {
    int t = blockIdx.x * blockDim.x + threadIdx.x;
    int e4 = t * 4;
    if (e4 >= n_edges) return;
    int4 r = *reinterpret_cast<const int4*>(&edges[e4]);
    int4 c = *reinterpret_cast<const int4*>(&edges[n_edges + e4]);
    if ((unsigned)r.x < (unsigned)n_nodes && (unsigned)c.x < (unsigned)n_nodes)
        col_sorted[atomicAdd(&cursor[r.x], 1)] = c.x;
    if ((unsigned)r.y < (unsigned)n_nodes && (unsigned)c.y < (unsigned)n_nodes)
        col_sorted[atomicAdd(&cursor[r.y], 1)] = c.y;
    if ((unsigned)r.z < (unsigned)n_nodes && (unsigned)c.z < (unsigned)n_nodes)
        col_sorted[atomicAdd(&cursor[r.z], 1)] = c.z;
    if ((unsigned)r.w < (unsigned)n_nodes && (unsigned)c.w < (unsigned)n_nodes)
        col_sorted[atomicAdd(&cursor[r.w], 1)] = c.w;
}

// ---------------------------------------------------------------------------
// aggregate: one wave per node. 4 edge-groups x 16 lanes; lane owns 8 feats
// (16 B of bf16 h). Cross-group reduce via shfl_xor. Fused bias + ReLU,
// f32 output.
// ---------------------------------------------------------------------------
__global__ __launch_bounds__(256) void aggregate_kernel(
        const unsigned short* __restrict__ h, const int* __restrict__ col_sorted,
        const int* __restrict__ offsets, const float* __restrict__ bias,
        float* __restrict__ out, int n_nodes) {
    const int node = blockIdx.x * 4 + (threadIdx.x >> 6);
    if (node >= n_nodes) return;
    const int l = threadIdx.x & 63;
    const int g = l >> 4;     // edge group 0..3
    const int fl = l & 15;    // feat group: feats fl*8 .. fl*8+7

    const int start = offsets[node];
    const int end   = offsets[node + 1];
    const unsigned short* hb = h + fl * 8;

    float a0 = 0.f, a1 = 0.f, a2 = 0.f, a3 = 0.f;
    float a4 = 0.f, a5 = 0.f, a6 = 0.f, a7 = 0.f;

    int e = start + g;
    // unrolled by 2 for memory-level parallelism
    for (; e + 4 < end; e += 8) {
        int c0 = col_sorted[e];
        int c1 = col_sorted[e + 4];
        uint4 r0 = *reinterpret_cast<const uint4*>(hb + (long long)c0 * OUT_FEAT);
        uint4 r1 = *reinterpret_cast<const uint4*>(hb + (long long)c1 * OUT_FEAT);
        a0 += bf_lo(r0.x); a1 += bf_hi(r0.x);
        a2 += bf_lo(r0.y); a3 += bf_hi(r0.y);
        a4 += bf_lo(r0.z); a5 += bf_hi(r0.z);
        a6 += bf_lo(r0.w); a7 += bf_hi(r0.w);
        a0 += bf_lo(r1.x); a1 += bf_hi(r1.x);
        a2 += bf_lo(r1.y); a3 += bf_hi(r1.y);
        a4 += bf_lo(r1.z); a5 += bf_hi(r1.z);
        a6 += bf_lo(r1.w); a7 += bf_hi(r1.w);
    }
    if (e < end) {
        int c0 = col_sorted[e];
        uint4 r0 = *reinterpret_cast<const uint4*>(hb + (long long)c0 * OUT_FEAT);
        a0 += bf_lo(r0.x); a1 += bf_hi(r0.x);
        a2 += bf_lo(r0.y); a3 += bf_hi(r0.y);
        a4 += bf_lo(r0.z); a5 += bf_hi(r0.z);
        a6 += bf_lo(r0.w); a7 += bf_hi(r0.w);
    }

    // reduce over the 4 edge groups (lanes differing in bits 4..5)
    #pragma unroll
    for (int d = 16; d <= 32; d <<= 1) {
        a0 += __shfl_xor(a0, d, 64); a1 += __shfl_xor(a1, d, 64);
        a2 += __shfl_xor(a2, d, 64); a3 += __shfl_xor(a3, d, 64);
        a4 += __shfl_xor(a4, d, 64); a5 += __shfl_xor(a5, d, 64);
        a6 += __shfl_xor(a6, d, 64); a7 += __shfl_xor(a7, d, 64);
    }

    if (g == 0) {
        const float* bp = bias + fl * 8;
        float4 b0 = *reinterpret_cast<const float4*>(bp);
        float4 b1 = *reinterpret_cast<const float4*>(bp + 4);
        float4 o0, o1;
        o0.x = fmaxf(a0 + b0.x, 0.f); o0.y = fmaxf(a1 + b0.y, 0.f);
        o0.z = fmaxf(a2 + b0.z, 0.f); o0.w = fmaxf(a3 + b0.w, 0.f);
        o1.x = fmaxf(a4 + b1.x, 0.f); o1.y = fmaxf(a5 + b1.y, 0.f);
        o1.z = fmaxf(a6 + b1.z, 0.f); o1.w = fmaxf(a7 + b1.w, 0.f);
        float* op = out + (long long)node * OUT_FEAT + fl * 8;
        *reinterpret_cast<float4*>(op) = o0;
        *reinterpret_cast<float4*>(op + 4) = o1;
    }
}

extern "C" void kernel_launch(void* const* d_in, const int* in_sizes, int n_in,
                              void* d_out, int out_size, void* d_ws, size_t ws_size,
                              hipStream_t stream) {
    const float* x      = (const float*)d_in[0];
    const int*   edges  = (const int*)d_in[1];
    const float* weight = (const float*)d_in[2];
    const float* bias   = (const float*)d_in[3];
    float* out = (float*)d_out;

    const int n_nodes = in_sizes[0] / IN_FEAT;   // 20000
    const int n_edges = in_sizes[1] / 2;         // 640000

    // workspace layout (16B aligned)
    char* ws = (char*)d_ws;
    size_t off = 0;
    unsigned short* h = (unsigned short*)(ws + off);
    off += (size_t)n_nodes * OUT_FEAT * 2;                       // 5.12 MB bf16
    unsigned short* wt = (unsigned short*)(ws + off);
    off += (size_t)IN_FEAT * OUT_FEAT * 2;                       // 64 KB bf16
    int* cursor = (int*)(ws + off);
    off += ((size_t)n_nodes * 4 + 15) & ~(size_t)15;             // 80 KB
    int* offsets = (int*)(ws + off);
    off += (((size_t)n_nodes + 1) * 4 + 15) & ~(size_t)15;
    int* col_sorted = (int*)(ws + off);
    off += (size_t)n_edges * 4;                                  // 2.56 MB

    // 0) zero degree counters
    hipMemsetAsync(cursor, 0, (size_t)n_nodes * 4, stream);

    // 1) W^T -> bf16  +  degree histogram (fused)
    int pc_threads = WT_THREADS + (n_edges + 3) / 4;
    prep_count_kernel<<<(pc_threads + 255) / 256, 256, 0, stream>>>(
        weight, wt, edges, cursor, n_edges, n_nodes);

    // 2) h = x @ W (bf16 MFMA, h stored bf16)
    gemm_kernel<<<(n_nodes + 63) / 64, 256, 0, stream>>>(x, wt, h, n_nodes);

    // 3) scan degrees -> offsets, cursor
    scan_kernel<<<1, SCAN_THREADS, 0, stream>>>(cursor, offsets, cursor, n_nodes);

    // 4) bucket-fill sources by destination
    fill_kernel<<<(n_edges / 4 + 255) / 256, 256, 0, stream>>>(
        edges, cursor, col_sorted, n_edges, n_nodes);

    // 5) gather-accumulate + bias + relu
    aggregate_kernel<<<(n_nodes + 3) / 4, 256, 0, stream>>>(
        h, col_sorted, offsets, bias, out, n_nodes);
}